// Round 1
// baseline (381.618 us; speedup 1.0000x reference)
//
#include <hip/hip_runtime.h>
#include <cstdint>

typedef float f32x4 __attribute__((ext_vector_type(4)));
typedef __bf16 bf16x8 __attribute__((ext_vector_type(8)));

typedef __attribute__((address_space(3))) uint32_t lds_u32;
typedef __attribute__((address_space(1))) const uint32_t glb_u32;

// async 16B global->LDS: dest = wave-uniform base + lane*16
#define GLOAD_LDS16(gp, lp) \
  __builtin_amdgcn_global_load_lds((glb_u32*)(uintptr_t)(gp), (lds_u32*)(uintptr_t)(lp), 16, 0, 0)

__device__ inline unsigned short f2bf(float f) {
  union { float f; uint32_t u; } v; v.f = f;
  uint32_t u = v.u;
  return (unsigned short)((u + 0x7fffu + ((u >> 16) & 1u)) >> 16); // RNE
}

// ---------------------------------------------------------------------------
// K1: transpose + bf16-cast the 4 weight matrices: Wt[n][k] = bf16(W[k][n])
// ---------------------------------------------------------------------------
__global__ void prep_w(const float* __restrict__ wq, const float* __restrict__ wk,
                       const float* __restrict__ wv, const float* __restrict__ wo,
                       unsigned short* __restrict__ wt)
{
  __shared__ float t[64][65];
  const int z = blockIdx.z;
  const float* W = (z == 0) ? wq : (z == 1) ? wk : (z == 2) ? wv : wo;
  unsigned short* Wt = wt + (size_t)z * 1048576;
  const int n0 = blockIdx.x * 64, k0 = blockIdx.y * 64;
  const int tx = threadIdx.x & 63, ty = threadIdx.x >> 6;
#pragma unroll
  for (int i = 0; i < 16; i++) {
    int row = i * 4 + ty;
    t[row][tx] = W[(size_t)(k0 + row) * 1024 + n0 + tx];
  }
  __syncthreads();
#pragma unroll
  for (int i = 0; i < 16; i++) {
    int row = i * 4 + ty;
    Wt[(size_t)(n0 + row) * 1024 + k0 + tx] = f2bf(t[tx][row]);
  }
}

// ---------------------------------------------------------------------------
// K1b: compose the two RoPE tables into one rotation table (128 pos x 32 pairs)
// ---------------------------------------------------------------------------
__global__ void comb_kernel(const float* __restrict__ ing, const float* __restrict__ seq,
                            float* __restrict__ cosc, float* __restrict__ sinc)
{
  int idx = blockIdx.x * 256 + threadIdx.x; // 0..4095
  int j = idx >> 5, i = idx & 31;
  float s1 = ing[j * 64 + i], c1 = ing[j * 64 + 32 + i];
  float s2 = seq[j * 64 + i], c2 = seq[j * 64 + 32 + i];
  cosc[idx] = c1 * c2 - s1 * s2;   // cos(t1+t2)
  sinc[idx] = s1 * c2 + c1 * s2;   // sin(t1+t2)
}

// ---------------------------------------------------------------------------
// K2: fp32 -> bf16 conversion of queries/keys/values (vectorized)
// ---------------------------------------------------------------------------
__global__ void cvt_kernel(const float* __restrict__ q, const float* __restrict__ k,
                           const float* __restrict__ v, unsigned short* __restrict__ dst)
{
  const int z = blockIdx.z;
  const float* src = (z == 0) ? q : (z == 1) ? k : v;
  unsigned short* d = dst + (size_t)z * 8388608;
  size_t i = ((size_t)blockIdx.x * 256 + threadIdx.x) * 4;
  float4 f = *(const float4*)&src[i];
  ushort4 o;
  o.x = f2bf(f.x); o.y = f2bf(f.y); o.z = f2bf(f.z); o.w = f2bf(f.w);
  *(ushort4*)&d[i] = o;
}

// ---------------------------------------------------------------------------
// K3/K5: 128x128-tile bf16 GEMM (A [M,K] row-major, B^T [N,K] row-major),
// global_load_lds(16B) staging, XOR-swizzled LDS granules, 16x16x32 MFMA.
//   final_mode=0: z in {0,1,2} -> Q(+RoPE), K(+RoPE), V(transposed) epilogues
//   final_mode=1: plain fp32 out + bias
// ---------------------------------------------------------------------------
__global__ __launch_bounds__(256, 2)
void gemm_bt(const unsigned short* __restrict__ Abase,
             const unsigned short* __restrict__ Bbase,
             const float* __restrict__ b0, const float* __restrict__ b1,
             const float* __restrict__ b2,
             unsigned short* __restrict__ qb, unsigned short* __restrict__ kb,
             unsigned short* __restrict__ vtb,
             float* __restrict__ outf,
             const float* __restrict__ cosc, const float* __restrict__ sinc,
             int final_mode)
{
  __shared__ __attribute__((aligned(16))) unsigned short As[128 * 32];
  __shared__ __attribute__((aligned(16))) unsigned short Bs[128 * 32];

  const int tid = threadIdx.x;
  const int lane = tid & 63;
  const int wave = tid >> 6;
  const int quad = lane >> 4;
  const int l15 = lane & 15;

  const int z = blockIdx.z;
  const int tileN = blockIdx.x * 128;
  const int tileM = blockIdx.y * 128;
  const int K = 1024;

  const unsigned short* A = Abase + (size_t)z * (8192u * 1024u);
  const unsigned short* B = Bbase + (size_t)z * (1024u * 1024u);

  const int wm = (wave >> 1) * 64;
  const int wn = (wave & 1) * 64;

  f32x4 acc[4][4];
#pragma unroll
  for (int a = 0; a < 4; a++)
#pragma unroll
    for (int n = 0; n < 4; n++)
      acc[a][n] = (f32x4){0.f, 0.f, 0.f, 0.f};

  for (int k0 = 0; k0 < K; k0 += 32) {
    // stage 8KB A-tile + 8KB B-tile; each wave: 2 A-chunks + 2 B-chunks of 1KB
#pragma unroll
    for (int cc0 = 0; cc0 < 2; cc0++) {
      int c = wave + cc0 * 4;          // chunk 0..7 (wave-uniform)
      int s = c * 64 + lane;           // granule slot 0..511
      int row = s >> 2;
      int koct = (s & 3) ^ ((row >> 1) & 3);   // XOR swizzle (2-way banks on read)
      const unsigned short* ga = A + (size_t)(tileM + row) * K + k0 + koct * 8;
      const unsigned short* gb = B + (size_t)(tileN + row) * K + k0 + koct * 8;
      GLOAD_LDS16(ga, &As[c * 512]);
      GLOAD_LDS16(gb, &Bs[c * 512]);
    }
    __syncthreads();   // compiler inserts vmcnt(0) drain before barrier

    bf16x8 af[4], bfr[4];
#pragma unroll
    for (int a = 0; a < 4; a++) {
      int r = wm + a * 16 + l15;
      int g = r * 4 + (quad ^ ((r >> 1) & 3));
      af[a] = *(const bf16x8*)&As[g * 8];
    }
#pragma unroll
    for (int n = 0; n < 4; n++) {
      int r = wn + n * 16 + l15;
      int g = r * 4 + (quad ^ ((r >> 1) & 3));
      bfr[n] = *(const bf16x8*)&Bs[g * 8];
    }
#pragma unroll
    for (int a = 0; a < 4; a++)
#pragma unroll
      for (int n = 0; n < 4; n++)
        acc[a][n] = __builtin_amdgcn_mfma_f32_16x16x32_bf16(af[a], bfr[n], acc[a][n], 0, 0, 0);
    __syncthreads();   // protect LDS for next stage
  }

  // ---------------- epilogue ----------------
  if (final_mode) {
#pragma unroll
    for (int n = 0; n < 4; n++) {
      int cg = tileN + wn + n * 16 + l15;
      float bias = b0[cg];
#pragma unroll
      for (int a = 0; a < 4; a++)
#pragma unroll
        for (int reg = 0; reg < 4; reg++) {
          int r = tileM + wm + a * 16 + quad * 4 + reg;
          outf[(size_t)r * 1024 + cg] = acc[a][n][reg] + bias;
        }
    }
  } else {
    const float* bias = (z == 0) ? b0 : (z == 1) ? b1 : b2;
    unsigned short* outq = (z == 0) ? qb : kb;
#pragma unroll
    for (int n = 0; n < 4; n++) {
      int cg = tileN + wn + n * 16 + l15;
      float bv_ = bias[cg];
      int h = cg >> 6, e = cg & 63;
#pragma unroll
      for (int a = 0; a < 4; a++)
#pragma unroll
        for (int reg = 0; reg < 4; reg++) {
          int r = tileM + wm + a * 16 + quad * 4 + reg;
          int bb = r >> 7, l = r & 127;
          float v = acc[a][n][reg] + bv_;
          if (z == 2) {
            // V: store transposed [B,H,E,S] for contiguous PV B-fragments
            vtb[(((size_t)bb * 16 + h) * 64 + e) * 128 + l] = f2bf(v);
          } else {
            // fused RoPE: cols sit in lane pairs (lane^1 = col^1)
            float other = __shfl_xor(v, 1);
            float cs = cosc[l * 32 + (e >> 1)];
            float sn = sinc[l * 32 + (e >> 1)];
            float res = v * cs + ((e & 1) ? other : -other) * sn;
            outq[(((size_t)bb * 16 + h) * 128 + l) * 64 + e] = f2bf(res);
          }
        }
    }
  }
}

// ---------------------------------------------------------------------------
// K4: attention. One block per (b,h). Scores in registers, in-register row
// softmax (16-lane shuffle reduce), fp32 attn out, P via LDS into PV MFMA.
// ---------------------------------------------------------------------------
__global__ __launch_bounds__(256, 2)
void attn_kernel(const unsigned short* __restrict__ qb,
                 const unsigned short* __restrict__ kb,
                 const unsigned short* __restrict__ vtb,
                 const unsigned char* __restrict__ mask,
                 float* __restrict__ attn_out,
                 unsigned short* __restrict__ ob)
{
  __shared__ __attribute__((aligned(16))) unsigned short Pb[128 * 136]; // +8 pad
  const int tid = threadIdx.x;
  const int lane = tid & 63;
  const int wave = tid >> 6;
  const int quad = lane >> 4;
  const int l15 = lane & 15;
  const int bh = blockIdx.x;       // b*16 + h
  const int b = bh >> 4;
  const int h = bh & 15;

  const unsigned short* q = qb + (size_t)bh * 128 * 64;
  const unsigned short* k = kb + (size_t)bh * 128 * 64;
  const unsigned short* vt = vtb + (size_t)bh * 64 * 128;

  // ---- scores = Q K^T : each wave owns 32 rows (2 m-tiles x 8 n-tiles) ----
  f32x4 sacc[2][8];
#pragma unroll
  for (int mt = 0; mt < 2; mt++)
#pragma unroll
    for (int nt = 0; nt < 8; nt++)
      sacc[mt][nt] = (f32x4){0.f, 0.f, 0.f, 0.f};

#pragma unroll
  for (int ks = 0; ks < 2; ks++) {
    bf16x8 aq[2], bk[8];
#pragma unroll
    for (int mt = 0; mt < 2; mt++)
      aq[mt] = *(const bf16x8*)&q[(size_t)(wave * 32 + mt * 16 + l15) * 64 + ks * 32 + quad * 8];
#pragma unroll
    for (int nt = 0; nt < 8; nt++)
      bk[nt] = *(const bf16x8*)&k[(size_t)(nt * 16 + l15) * 64 + ks * 32 + quad * 8];
#pragma unroll
    for (int mt = 0; mt < 2; mt++)
#pragma unroll
      for (int nt = 0; nt < 8; nt++)
        sacc[mt][nt] = __builtin_amdgcn_mfma_f32_16x16x32_bf16(aq[mt], bk[nt], sacc[mt][nt], 0, 0, 0);
  }

  // ---- softmax per row (row r lives in one 16-lane group, one reg) ----
  const float scale = 0.125f;
#pragma unroll
  for (int mt = 0; mt < 2; mt++) {
#pragma unroll
    for (int reg = 0; reg < 4; reg++) {
      int r = wave * 32 + mt * 16 + quad * 4 + reg;
      const unsigned char* mrow = mask + ((size_t)b * 128 + r) * 128;
      float sv[8];
#pragma unroll
      for (int nt = 0; nt < 8; nt++) {
        float x = sacc[mt][nt][reg] * scale;
        if (mrow[nt * 16 + l15]) x = -__builtin_inff();
        sv[nt] = x;
      }
      float m = sv[0];
#pragma unroll
      for (int nt = 1; nt < 8; nt++) m = fmaxf(m, sv[nt]);
#pragma unroll
      for (int off = 1; off < 16; off <<= 1) m = fmaxf(m, __shfl_xor(m, off));
      float s = 0.f;
#pragma unroll
      for (int nt = 0; nt < 8; nt++) { sv[nt] = __expf(sv[nt] - m); s += sv[nt]; }
#pragma unroll
      for (int off = 1; off < 16; off <<= 1) s += __shfl_xor(s, off);
      float inv = 1.0f / s;
      float* arow = attn_out + ((size_t)bh * 128 + r) * 128;
#pragma unroll
      for (int nt = 0; nt < 8; nt++) {
        float p = sv[nt] * inv;
        arow[nt * 16 + l15] = p;                    // required fp32 attn output
        Pb[r * 136 + nt * 16 + l15] = f2bf(p);      // bf16 P for PV MFMA
      }
    }
  }
  __syncthreads();

  // ---- O = P V ----
  f32x4 oacc[2][4];
#pragma unroll
  for (int mt = 0; mt < 2; mt++)
#pragma unroll
    for (int nt = 0; nt < 4; nt++)
      oacc[mt][nt] = (f32x4){0.f, 0.f, 0.f, 0.f};

#pragma unroll
  for (int ks = 0; ks < 4; ks++) {
    bf16x8 bv[4], ap[2];
#pragma unroll
    for (int nt = 0; nt < 4; nt++)
      bv[nt] = *(const bf16x8*)&vt[(size_t)(nt * 16 + l15) * 128 + ks * 32 + quad * 8];
#pragma unroll
    for (int mt = 0; mt < 2; mt++)
      ap[mt] = *(const bf16x8*)&Pb[(size_t)(wave * 32 + mt * 16 + l15) * 136 + ks * 32 + quad * 8];
#pragma unroll
    for (int mt = 0; mt < 2; mt++)
#pragma unroll
      for (int nt = 0; nt < 4; nt++)
        oacc[mt][nt] = __builtin_amdgcn_mfma_f32_16x16x32_bf16(ap[mt], bv[nt], oacc[mt][nt], 0, 0, 0);
  }

  // ---- write O as bf16 [B, L, H*E] for the output projection ----
#pragma unroll
  for (int mt = 0; mt < 2; mt++)
#pragma unroll
    for (int nt = 0; nt < 4; nt++)
#pragma unroll
      for (int reg = 0; reg < 4; reg++) {
        int r = wave * 32 + mt * 16 + quad * 4 + reg;   // l
        int e = nt * 16 + l15;
        ob[((size_t)b * 128 + r) * 1024 + h * 64 + e] = f2bf(oacc[mt][nt][reg]);
      }
}

// ---------------------------------------------------------------------------
extern "C" void kernel_launch(void* const* d_in, const int* in_sizes, int n_in,
                              void* d_out, int out_size, void* d_ws, size_t ws_size,
                              hipStream_t stream)
{
  const float* queries = (const float*)d_in[0];
  const float* keys    = (const float*)d_in[1];
  const float* values  = (const float*)d_in[2];
  const unsigned char* mask = (const unsigned char*)d_in[3];
  const float* Wq = (const float*)d_in[4];
  const float* bq = (const float*)d_in[5];
  const float* Wk = (const float*)d_in[6];
  const float* bk = (const float*)d_in[7];
  const float* Wv = (const float*)d_in[8];
  const float* bv = (const float*)d_in[9];
  const float* Wo = (const float*)d_in[10];
  const float* bo = (const float*)d_in[11];
  const float* ping = (const float*)d_in[12];
  const float* pseq = (const float*)d_in[13];

  float* out  = (float*)d_out;           // [8192,1024] fp32
  float* attn = out + 8388608;           // [64,16,128,128] fp32 (64 MB)
  // use the attn region as scratch for bf16 inputs (48 MB); K4 overwrites it
  unsigned short* Xbf = (unsigned short*)attn;

  char* ws = (char*)d_ws;
  unsigned short* Wt  = (unsigned short*)(ws);                          // 8 MB
  float* cosc = (float*)(ws + 8388608);                                 // 16 KB
  float* sinc = (float*)(ws + 8388608 + 16384);                         // 16 KB
  unsigned short* qbuf = (unsigned short*)(ws + 8421376);               // 16 MB
  unsigned short* kbuf = (unsigned short*)(ws + 8421376 + 16777216);    // 16 MB
  unsigned short* vtbuf= (unsigned short*)(ws + 8421376 + 2*16777216);  // 16 MB
  unsigned short* obuf = (unsigned short*)(ws + 8421376 + 3*16777216);  // 16 MB

  prep_w<<<dim3(16, 16, 4), 256, 0, stream>>>(Wq, Wk, Wv, Wo, Wt);
  comb_kernel<<<16, 256, 0, stream>>>(ping, pseq, cosc, sinc);
  cvt_kernel<<<dim3(8192, 1, 3), 256, 0, stream>>>(queries, keys, values, Xbf);
  gemm_bt<<<dim3(8, 64, 3), 256, 0, stream>>>(Xbf, Wt, bq, bk, bv,
                                              qbuf, kbuf, vtbuf, nullptr,
                                              cosc, sinc, 0);
  attn_kernel<<<dim3(1024), 256, 0, stream>>>(qbuf, kbuf, vtbuf, mask, attn, obuf);
  gemm_bt<<<dim3(8, 64, 1), 256, 0, stream>>>(obuf, Wt + 3 * 1048576, bo, bo, bo,
                                              qbuf, kbuf, vtbuf, out,
                                              cosc, sinc, 1);
}

// Round 2
// 351.717 us; speedup vs baseline: 1.0850x; 1.0850x over previous
//
#include <hip/hip_runtime.h>
#include <cstdint>

typedef float f32x4 __attribute__((ext_vector_type(4)));
typedef __bf16 bf16x8 __attribute__((ext_vector_type(8)));

typedef __attribute__((address_space(3))) uint32_t lds_u32;
typedef __attribute__((address_space(1))) const uint32_t glb_u32;

// async 16B global->LDS: dest = wave-uniform base + lane*16
#define GLOAD_LDS16(gp, lp) \
  __builtin_amdgcn_global_load_lds((glb_u32*)(uintptr_t)(gp), (lds_u32*)(uintptr_t)(lp), 16, 0, 0)

__device__ inline unsigned short f2bf(float f) {
  union { float f; uint32_t u; } v; v.f = f;
  uint32_t u = v.u;
  return (unsigned short)((u + 0x7fffu + ((u >> 16) & 1u)) >> 16); // RNE
}

// ---------------------------------------------------------------------------
// K1: transpose + bf16-cast the 4 weight matrices: Wt[n][k] = bf16(W[k][n])
// ---------------------------------------------------------------------------
__global__ void prep_w(const float* __restrict__ wq, const float* __restrict__ wk,
                       const float* __restrict__ wv, const float* __restrict__ wo,
                       unsigned short* __restrict__ wt)
{
  __shared__ float t[64][65];
  const int z = blockIdx.z;
  const float* W = (z == 0) ? wq : (z == 1) ? wk : (z == 2) ? wv : wo;
  unsigned short* Wt = wt + (size_t)z * 1048576;
  const int n0 = blockIdx.x * 64, k0 = blockIdx.y * 64;
  const int tx = threadIdx.x & 63, ty = threadIdx.x >> 6;
#pragma unroll
  for (int i = 0; i < 16; i++) {
    int row = i * 4 + ty;
    t[row][tx] = W[(size_t)(k0 + row) * 1024 + n0 + tx];
  }
  __syncthreads();
#pragma unroll
  for (int i = 0; i < 16; i++) {
    int row = i * 4 + ty;
    Wt[(size_t)(n0 + row) * 1024 + k0 + tx] = f2bf(t[tx][row]);
  }
}

// ---------------------------------------------------------------------------
// K1b: compose the two RoPE tables into one rotation table (128 pos x 32 pairs)
// ---------------------------------------------------------------------------
__global__ void comb_kernel(const float* __restrict__ ing, const float* __restrict__ seq,
                            float* __restrict__ cosc, float* __restrict__ sinc)
{
  int idx = blockIdx.x * 256 + threadIdx.x; // 0..4095
  int j = idx >> 5, i = idx & 31;
  float s1 = ing[j * 64 + i], c1 = ing[j * 64 + 32 + i];
  float s2 = seq[j * 64 + i], c2 = seq[j * 64 + 32 + i];
  cosc[idx] = c1 * c2 - s1 * s2;   // cos(t1+t2)
  sinc[idx] = s1 * c2 + c1 * s2;   // sin(t1+t2)
}

// ---------------------------------------------------------------------------
// K2: fp32 -> bf16 conversion of queries/keys/values (vectorized)
// ---------------------------------------------------------------------------
__global__ void cvt_kernel(const float* __restrict__ q, const float* __restrict__ k,
                           const float* __restrict__ v, unsigned short* __restrict__ dst)
{
  const int z = blockIdx.z;
  const float* src = (z == 0) ? q : (z == 1) ? k : v;
  unsigned short* d = dst + (size_t)z * 8388608;
  size_t i = ((size_t)blockIdx.x * 256 + threadIdx.x) * 4;
  float4 f = *(const float4*)&src[i];
  ushort4 o;
  o.x = f2bf(f.x); o.y = f2bf(f.y); o.z = f2bf(f.z); o.w = f2bf(f.w);
  *(ushort4*)&d[i] = o;
}

// ---------------------------------------------------------------------------
// K3/K5: 128x128-tile bf16 GEMM, BK=64 (2 barriers per 64-K: half the vmcnt(0)
// drains of the BK=32 version), global_load_lds(16B) staging, XOR-swizzled
// LDS granules, 16x16x32 MFMA. Grid is M-fastest so the 8 N-tile blocks that
// share an A-tile map to the same XCD (linear id % 8 == m-tile % 8) -> A-tile
// stays L2-resident across n rounds.
//   final_mode=0: z in {0,1,2} -> Q(+RoPE), K(+RoPE), V(transposed) epilogues
//   final_mode=1: plain fp32 out + bias
// ---------------------------------------------------------------------------
__global__ __launch_bounds__(256, 2)
void gemm_bt(const unsigned short* __restrict__ Abase,
             const unsigned short* __restrict__ Bbase,
             const float* __restrict__ b0, const float* __restrict__ b1,
             const float* __restrict__ b2,
             unsigned short* __restrict__ qb, unsigned short* __restrict__ kb,
             unsigned short* __restrict__ vtb,
             float* __restrict__ outf,
             const float* __restrict__ cosc, const float* __restrict__ sinc,
             int final_mode)
{
  __shared__ __attribute__((aligned(16))) unsigned short As[128 * 64];
  __shared__ __attribute__((aligned(16))) unsigned short Bs[128 * 64];

  const int tid = threadIdx.x;
  const int lane = tid & 63;
  const int wave = tid >> 6;
  const int quad = lane >> 4;
  const int l15 = lane & 15;

  const int z = blockIdx.z;
  const int tileM = blockIdx.x * 128;   // M fastest -> XCD-local A reuse
  const int tileN = blockIdx.y * 128;
  const int K = 1024;

  const unsigned short* A = Abase + (size_t)z * (8192u * 1024u);
  const unsigned short* B = Bbase + (size_t)z * (1024u * 1024u);

  const int wm = (wave >> 1) * 64;
  const int wn = (wave & 1) * 64;

  f32x4 acc[4][4];
#pragma unroll
  for (int a = 0; a < 4; a++)
#pragma unroll
    for (int n = 0; n < 4; n++)
      acc[a][n] = (f32x4){0.f, 0.f, 0.f, 0.f};

  for (int k0 = 0; k0 < K; k0 += 64) {
    // stage 16KB A-tile + 16KB B-tile; each wave: 4 A-chunks + 4 B-chunks (1KB)
#pragma unroll
    for (int cc = 0; cc < 4; cc++) {
      int c = wave * 4 + cc;           // chunk 0..15 (wave-uniform)
      int s = c * 64 + lane;           // granule slot 0..1023
      int row = s >> 3;                // 8 granules (of 8 bf16) per row
      int gc = (s & 7) ^ (row & 7);    // XOR swizzle: read groups spread banks
      const unsigned short* ga = A + (size_t)(tileM + row) * K + k0 + gc * 8;
      const unsigned short* gb = B + (size_t)(tileN + row) * K + k0 + gc * 8;
      GLOAD_LDS16(ga, &As[c * 512]);
      GLOAD_LDS16(gb, &Bs[c * 512]);
    }
    __syncthreads();   // compiler inserts vmcnt(0) drain before barrier

#pragma unroll
    for (int ks = 0; ks < 2; ks++) {
      bf16x8 af[4], bfr[4];
#pragma unroll
      for (int a = 0; a < 4; a++) {
        int r = wm + a * 16 + l15;
        int cp = (ks * 4 + quad) ^ (r & 7);
        af[a] = *(const bf16x8*)&As[(r * 8 + cp) * 8];
      }
#pragma unroll
      for (int n = 0; n < 4; n++) {
        int r = wn + n * 16 + l15;
        int cp = (ks * 4 + quad) ^ (r & 7);
        bfr[n] = *(const bf16x8*)&Bs[(r * 8 + cp) * 8];
      }
#pragma unroll
      for (int a = 0; a < 4; a++)
#pragma unroll
        for (int n = 0; n < 4; n++)
          acc[a][n] = __builtin_amdgcn_mfma_f32_16x16x32_bf16(af[a], bfr[n], acc[a][n], 0, 0, 0);
    }
    __syncthreads();   // protect LDS for next stage
  }

  // ---------------- epilogue ----------------
  if (final_mode) {
#pragma unroll
    for (int n = 0; n < 4; n++) {
      int cg = tileN + wn + n * 16 + l15;
      float bias = b0[cg];
#pragma unroll
      for (int a = 0; a < 4; a++)
#pragma unroll
        for (int reg = 0; reg < 4; reg++) {
          int r = tileM + wm + a * 16 + quad * 4 + reg;
          outf[(size_t)r * 1024 + cg] = acc[a][n][reg] + bias;
        }
    }
  } else {
    const float* bias = (z == 0) ? b0 : (z == 1) ? b1 : b2;
    unsigned short* outq = (z == 0) ? qb : kb;
#pragma unroll
    for (int n = 0; n < 4; n++) {
      int cg = tileN + wn + n * 16 + l15;
      float bv_ = bias[cg];
      int h = cg >> 6, e = cg & 63;
#pragma unroll
      for (int a = 0; a < 4; a++)
#pragma unroll
        for (int reg = 0; reg < 4; reg++) {
          int r = tileM + wm + a * 16 + quad * 4 + reg;
          int bb = r >> 7, l = r & 127;
          float v = acc[a][n][reg] + bv_;
          if (z == 2) {
            // V: store transposed [B,H,E,S] for contiguous PV B-fragments
            vtb[(((size_t)bb * 16 + h) * 64 + e) * 128 + l] = f2bf(v);
          } else {
            // fused RoPE: cols sit in lane pairs (lane^1 = col^1)
            float other = __shfl_xor(v, 1);
            float cs = cosc[l * 32 + (e >> 1)];
            float sn = sinc[l * 32 + (e >> 1)];
            float res = v * cs + ((e & 1) ? other : -other) * sn;
            outq[(((size_t)bb * 16 + h) * 128 + l) * 64 + e] = f2bf(res);
          }
        }
    }
  }
}

// ---------------------------------------------------------------------------
// K4: attention. One block per (b,h). Scores in registers, in-register row
// softmax (16-lane shuffle reduce), fp32 attn out, P via LDS into PV MFMA.
// ---------------------------------------------------------------------------
__global__ __launch_bounds__(256, 2)
void attn_kernel(const unsigned short* __restrict__ qb,
                 const unsigned short* __restrict__ kb,
                 const unsigned short* __restrict__ vtb,
                 const unsigned char* __restrict__ mask,
                 float* __restrict__ attn_out,
                 unsigned short* __restrict__ ob)
{
  __shared__ __attribute__((aligned(16))) unsigned short Pb[128 * 136]; // +8 pad
  const int tid = threadIdx.x;
  const int lane = tid & 63;
  const int wave = tid >> 6;
  const int quad = lane >> 4;
  const int l15 = lane & 15;
  const int bh = blockIdx.x;       // b*16 + h
  const int b = bh >> 4;
  const int h = bh & 15;

  const unsigned short* q = qb + (size_t)bh * 128 * 64;
  const unsigned short* k = kb + (size_t)bh * 128 * 64;
  const unsigned short* vt = vtb + (size_t)bh * 64 * 128;

  // ---- scores = Q K^T : each wave owns 32 rows (2 m-tiles x 8 n-tiles) ----
  f32x4 sacc[2][8];
#pragma unroll
  for (int mt = 0; mt < 2; mt++)
#pragma unroll
    for (int nt = 0; nt < 8; nt++)
      sacc[mt][nt] = (f32x4){0.f, 0.f, 0.f, 0.f};

#pragma unroll
  for (int ks = 0; ks < 2; ks++) {
    bf16x8 aq[2], bk[8];
#pragma unroll
    for (int mt = 0; mt < 2; mt++)
      aq[mt] = *(const bf16x8*)&q[(size_t)(wave * 32 + mt * 16 + l15) * 64 + ks * 32 + quad * 8];
#pragma unroll
    for (int nt = 0; nt < 8; nt++)
      bk[nt] = *(const bf16x8*)&k[(size_t)(nt * 16 + l15) * 64 + ks * 32 + quad * 8];
#pragma unroll
    for (int mt = 0; mt < 2; mt++)
#pragma unroll
      for (int nt = 0; nt < 8; nt++)
        sacc[mt][nt] = __builtin_amdgcn_mfma_f32_16x16x32_bf16(aq[mt], bk[nt], sacc[mt][nt], 0, 0, 0);
  }

  // ---- softmax per row (row r lives in one 16-lane group, one reg) ----
  const float scale = 0.125f;
#pragma unroll
  for (int mt = 0; mt < 2; mt++) {
#pragma unroll
    for (int reg = 0; reg < 4; reg++) {
      int r = wave * 32 + mt * 16 + quad * 4 + reg;
      const unsigned char* mrow = mask + ((size_t)b * 128 + r) * 128;
      float sv[8];
#pragma unroll
      for (int nt = 0; nt < 8; nt++) {
        float x = sacc[mt][nt][reg] * scale;
        if (mrow[nt * 16 + l15]) x = -__builtin_inff();
        sv[nt] = x;
      }
      float m = sv[0];
#pragma unroll
      for (int nt = 1; nt < 8; nt++) m = fmaxf(m, sv[nt]);
#pragma unroll
      for (int off = 1; off < 16; off <<= 1) m = fmaxf(m, __shfl_xor(m, off));
      float s = 0.f;
#pragma unroll
      for (int nt = 0; nt < 8; nt++) { sv[nt] = __expf(sv[nt] - m); s += sv[nt]; }
#pragma unroll
      for (int off = 1; off < 16; off <<= 1) s += __shfl_xor(s, off);
      float inv = 1.0f / s;
      float* arow = attn_out + ((size_t)bh * 128 + r) * 128;
#pragma unroll
      for (int nt = 0; nt < 8; nt++) {
        float p = sv[nt] * inv;
        arow[nt * 16 + l15] = p;                    // required fp32 attn output
        Pb[r * 136 + nt * 16 + l15] = f2bf(p);      // bf16 P for PV MFMA
      }
    }
  }
  __syncthreads();

  // ---- O = P V ----
  f32x4 oacc[2][4];
#pragma unroll
  for (int mt = 0; mt < 2; mt++)
#pragma unroll
    for (int nt = 0; nt < 4; nt++)
      oacc[mt][nt] = (f32x4){0.f, 0.f, 0.f, 0.f};

#pragma unroll
  for (int ks = 0; ks < 4; ks++) {
    bf16x8 bv[4], ap[2];
#pragma unroll
    for (int nt = 0; nt < 4; nt++)
      bv[nt] = *(const bf16x8*)&vt[(size_t)(nt * 16 + l15) * 128 + ks * 32 + quad * 8];
#pragma unroll
    for (int mt = 0; mt < 2; mt++)
      ap[mt] = *(const bf16x8*)&Pb[(size_t)(wave * 32 + mt * 16 + l15) * 136 + ks * 32 + quad * 8];
#pragma unroll
    for (int mt = 0; mt < 2; mt++)
#pragma unroll
      for (int nt = 0; nt < 4; nt++)
        oacc[mt][nt] = __builtin_amdgcn_mfma_f32_16x16x32_bf16(ap[mt], bv[nt], oacc[mt][nt], 0, 0, 0);
  }

  // ---- write O as bf16 [B, L, H*E] for the output projection ----
#pragma unroll
  for (int mt = 0; mt < 2; mt++)
#pragma unroll
    for (int nt = 0; nt < 4; nt++)
#pragma unroll
      for (int reg = 0; reg < 4; reg++) {
        int r = wave * 32 + mt * 16 + quad * 4 + reg;   // l
        int e = nt * 16 + l15;
        ob[((size_t)b * 128 + r) * 1024 + h * 64 + e] = f2bf(oacc[mt][nt][reg]);
      }
}

// ---------------------------------------------------------------------------
extern "C" void kernel_launch(void* const* d_in, const int* in_sizes, int n_in,
                              void* d_out, int out_size, void* d_ws, size_t ws_size,
                              hipStream_t stream)
{
  const float* queries = (const float*)d_in[0];
  const float* keys    = (const float*)d_in[1];
  const float* values  = (const float*)d_in[2];
  const unsigned char* mask = (const unsigned char*)d_in[3];
  const float* Wq = (const float*)d_in[4];
  const float* bq = (const float*)d_in[5];
  const float* Wk = (const float*)d_in[6];
  const float* bk = (const float*)d_in[7];
  const float* Wv = (const float*)d_in[8];
  const float* bv = (const float*)d_in[9];
  const float* Wo = (const float*)d_in[10];
  const float* bo = (const float*)d_in[11];
  const float* ping = (const float*)d_in[12];
  const float* pseq = (const float*)d_in[13];

  float* out  = (float*)d_out;           // [8192,1024] fp32
  float* attn = out + 8388608;           // [64,16,128,128] fp32 (64 MB)
  // use the attn region as scratch for bf16 inputs (48 MB); K4 overwrites it
  unsigned short* Xbf = (unsigned short*)attn;

  char* ws = (char*)d_ws;
  unsigned short* Wt  = (unsigned short*)(ws);                          // 8 MB
  float* cosc = (float*)(ws + 8388608);                                 // 16 KB
  float* sinc = (float*)(ws + 8388608 + 16384);                         // 16 KB
  unsigned short* qbuf = (unsigned short*)(ws + 8421376);               // 16 MB
  unsigned short* kbuf = (unsigned short*)(ws + 8421376 + 16777216);    // 16 MB
  unsigned short* vtbuf= (unsigned short*)(ws + 8421376 + 2*16777216);  // 16 MB
  unsigned short* obuf = (unsigned short*)(ws + 8421376 + 3*16777216);  // 16 MB

  prep_w<<<dim3(16, 16, 4), 256, 0, stream>>>(Wq, Wk, Wv, Wo, Wt);
  comb_kernel<<<16, 256, 0, stream>>>(ping, pseq, cosc, sinc);
  cvt_kernel<<<dim3(8192, 1, 3), 256, 0, stream>>>(queries, keys, values, Xbf);
  gemm_bt<<<dim3(64, 8, 3), 256, 0, stream>>>(Xbf, Wt, bq, bk, bv,
                                              qbuf, kbuf, vtbuf, nullptr,
                                              cosc, sinc, 0);
  attn_kernel<<<dim3(1024), 256, 0, stream>>>(qbuf, kbuf, vtbuf, mask, attn, obuf);
  gemm_bt<<<dim3(64, 8, 1), 256, 0, stream>>>(obuf, Wt + 3 * 1048576, bo, bo, bo,
                                              qbuf, kbuf, vtbuf, out,
                                              cosc, sinc, 1);
}